// Round 12
// baseline (219.657 us; speedup 1.0000x reference)
//
#include <hip/hip_runtime.h>
#include <hip/hip_bf16.h>

typedef __hip_bfloat16 bf16;
typedef unsigned short ushort_t;
typedef unsigned int uint_t;
typedef __attribute__((ext_vector_type(8))) __bf16 bf16x8;
typedef __attribute__((ext_vector_type(8))) ushort_t u16x8;
typedef __attribute__((ext_vector_type(4))) ushort_t u16x4;
typedef __attribute__((ext_vector_type(4))) float f32x4;

#define BB 4
#define LL 1024
#define DM 512
#define DS 16
#define DI 1024
#define ROWS 4096
#define NC 128      // chunks over time
#define CT 8        // steps per chunk
#define NCH 8       // channels per scan block
#define NDTX 1152   // padded N for fused [delta | ssm] GEMM (9*128)

__device__ __forceinline__ float b2f(bf16 v) { return __bfloat162float(v); }

__device__ __forceinline__ float load_flag(const void* src, int i, int isbf)
{
    return isbf ? b2f(((const bf16*)src)[i]) : ((const float*)src)[i];
}

__device__ __forceinline__ ushort_t f2b_bits(float v)
{
    bf16 t = __float2bfloat16(v);
    return *(ushort_t*)&t;
}

__device__ __forceinline__ float bits2f(ushort_t u)
{
    uint_t w = ((uint_t)u) << 16;
    return __uint_as_float(w);
}

// Per-block dtype detection: sample 256 16-bit words of W_dt (scale 0.02).
__device__ __forceinline__ int detect_local(const ushort_t* wdt)
{
    __shared__ int bad;
    if (threadIdx.x == 0) bad = 0;
    __syncthreads();
    ushort_t u = wdt[threadIdx.x & 255];
    if (((u >> 7) & 0xFF) >= 127) atomicAdd(&bad, 1);
    __syncthreads();
    return (bad <= 8) ? 1 : 0;   // 1 = bf16 inputs
}

// ---------------------------------------------------------------------------
// ALL prep in one launch. Block ranges:
//   [0,2048):      pack_x  (x -> clipped bf16, 4 elems/thread)
//   [2048,4640):   weight transposes (LDS 32x32 tile)
//   [4640,5057):   small params + dtx bias + WtDtx pad-zero rows 1056..1151
// ---------------------------------------------------------------------------
__global__ __launch_bounds__(256)
void prep_all(const void* x, const void* Win, const void* Wdt, const void* Wx,
              const void* Wout, const void* cw, const void* cb, const void* Alog,
              const void* Dsk, const void* gam, const void* bet, const void* bdtin,
              bf16* __restrict__ xbf, bf16* __restrict__ WtIn,
              bf16* __restrict__ WtDtx, bf16* __restrict__ WtOut,
              float* __restrict__ ccw, float* __restrict__ ccb,
              float* __restrict__ cAlg, float* __restrict__ cDsk,
              float* __restrict__ cgam, float* __restrict__ cbet,
              float* __restrict__ bdtx)
{
    const int isbf = detect_local((const ushort_t*)Wdt);
    int blk = blockIdx.x;

    if (blk < 2048) {
        int idx = blk * 256 + threadIdx.x;
        float v[4];
        if (isbf) {
            uint2 raw = ((const uint2*)x)[idx];
            v[0] = __uint_as_float(raw.x << 16);
            v[1] = __uint_as_float(raw.x & 0xFFFF0000u);
            v[2] = __uint_as_float(raw.y << 16);
            v[3] = __uint_as_float(raw.y & 0xFFFF0000u);
        } else {
            float4 raw = ((const float4*)x)[idx];
            v[0] = raw.x; v[1] = raw.y; v[2] = raw.z; v[3] = raw.w;
        }
        uint_t b0, b1;
        b0 = f2b_bits(fminf(fmaxf(v[0], -10.f), 10.f))
           | ((uint_t)f2b_bits(fminf(fmaxf(v[1], -10.f), 10.f)) << 16);
        b1 = f2b_bits(fminf(fmaxf(v[2], -10.f), 10.f))
           | ((uint_t)f2b_bits(fminf(fmaxf(v[3], -10.f), 10.f)) << 16);
        uint2 ow; ow.x = b0; ow.y = b1;
        ((uint2*)xbf)[idx] = ow;
    } else if (blk < 4640) {
        int tb = blk - 2048;
        const void* src; bf16* dst; int K, Nsrc, tpr;
        if (tb < 1024)      { src = Win;  dst = WtIn;   K = 512;  Nsrc = 2048; tpr = 64; }
        else if (tb < 2048) { tb -= 1024; src = Wdt;  dst = WtDtx; K = 1024; Nsrc = 1024; tpr = 32; }
        else if (tb < 2080) { tb -= 2048; src = Wx;   dst = WtDtx + 1024 * 1024; K = 1024; Nsrc = 32; tpr = 1; }
        else                { tb -= 2080; src = Wout; dst = WtOut;  K = 1024; Nsrc = 512;  tpr = 16; }
        int k0 = (tb / tpr) * 32, n0 = (tb % tpr) * 32;

        __shared__ float tile[32][33];
        int tx = threadIdx.x & 31, ty = threadIdx.x >> 5;
        #pragma unroll
        for (int j = 0; j < 4; ++j)
            tile[ty + 8 * j][tx] = load_flag(src, (k0 + ty + 8 * j) * Nsrc + n0 + tx, isbf);
        __syncthreads();
        #pragma unroll
        for (int j = 0; j < 4; ++j)
            dst[(size_t)(n0 + ty + 8 * j) * K + k0 + tx] = __float2bfloat16(tile[tx][ty + 8 * j]);
    } else {
        int i = (blk - 4640) * 256 + threadIdx.x;
        if (i < 4096)        ccw[i] = load_flag(cw, i, isbf);
        else if (i < 5120)   ccb[i - 4096] = load_flag(cb, i - 4096, isbf);
        else if (i < 5136)   cAlg[i - 5120] = load_flag(Alog, i - 5120, isbf);
        else if (i < 6160)   cDsk[i - 5136] = load_flag(Dsk, i - 5136, isbf);
        else if (i < 6672)   cgam[i - 6160] = load_flag(gam, i - 6160, isbf);
        else if (i < 7184)   cbet[i - 6672] = load_flag(bet, i - 6672, isbf);
        else if (i < 8336) {
            int j = i - 7184;
            bdtx[j] = (j < DI) ? load_flag(bdtin, j, isbf) : 0.f;
        } else if (i < 106640) {
            (WtDtx + 1056 * 1024)[i - 8336] = __float2bfloat16(0.f);
        }
    }
}

// ---------------------------------------------------------------------------
// MFMA bf16 GEMM: C = A[M][K] * Bt[N][K]^T (+bias).
// TM x TN tile, 4 waves (2x2), 16x16x32 frags, BK=64, global_load_lds
// width-16 with XOR 8-chunk swizzle.
// OT: store transposed DT[n][m] bf16 (u16x4). OBF: bf16 row-major.
// SPLIT: columns n in [1024,1088) stored row-major bf16 to Cv2 (stride 64,
// col n-1024); n >= 1088 dropped (padding). Used for fused delta|ssm GEMM.
// ---------------------------------------------------------------------------
__device__ __forceinline__ void gload16(const bf16* g, ushort_t* l)
{
    __builtin_amdgcn_global_load_lds(
        (const __attribute__((address_space(1))) void*)g,
        (__attribute__((address_space(3))) void*)l, 16, 0, 0);
}

template <int TM, int TN, bool OBF, bool OT, bool SPLIT>
__global__ __launch_bounds__(256)
void gemm_mfma(const bf16* __restrict__ A, const bf16* __restrict__ Bt,
               const float* __restrict__ bias, void* __restrict__ Cv,
               void* __restrict__ Cv2, int M, int N, int K)
{
    constexpr int MI = TM / 32, NJ = TN / 32;
    constexpr int NQA = TM * 8 / 256;
    constexpr int NQB = TN * 8 / 256;
    __shared__ ushort_t As[TM * 64];
    __shared__ ushort_t Bs[TN * 64];

    const int tid = threadIdx.x;
    const int lane = tid & 63;
    const int w = tid >> 6;
    const int wr = w >> 1, wc = w & 1;
    const int m0 = blockIdx.y * TM;
    const int n0 = blockIdx.x * TN;

    const bf16* gA[NQA]; ushort_t* lA[NQA];
    #pragma unroll
    for (int q = 0; q < NQA; ++q) {
        int p = q * 256 + tid;
        int row = p >> 3, kc = ((p & 7) - row) & 7;
        gA[q] = A + (size_t)(m0 + row) * K + kc * 8;
        lA[q] = &As[(q * 256 + w * 64) * 8];
    }
    const bf16* gB[NQB]; ushort_t* lB[NQB];
    #pragma unroll
    for (int q = 0; q < NQB; ++q) {
        int p = q * 256 + tid;
        int row = p >> 3, kc = ((p & 7) - row) & 7;
        gB[q] = Bt + (size_t)(n0 + row) * K + kc * 8;
        lB[q] = &Bs[(q * 256 + w * 64) * 8];
    }

    f32x4 acc[MI][NJ];
    #pragma unroll
    for (int i = 0; i < MI; ++i)
        #pragma unroll
        for (int j = 0; j < NJ; ++j)
            acc[i][j] = (f32x4){0.f, 0.f, 0.f, 0.f};

    const int ko = lane >> 4;
    const int ml = lane & 15;

    for (int k0 = 0; k0 < K; k0 += 64) {
        #pragma unroll
        for (int q = 0; q < NQA; ++q) gload16(gA[q] + k0, lA[q]);
        #pragma unroll
        for (int q = 0; q < NQB; ++q) gload16(gB[q] + k0, lB[q]);
        __syncthreads();

        #pragma unroll
        for (int half = 0; half < 2; ++half) {
            bf16x8 af[MI], bfr[NJ];
            #pragma unroll
            for (int i = 0; i < MI; ++i) {
                int m = wr * (TM / 2) + i * 16 + ml;
                af[i] = *(const bf16x8*)&As[(m * 8 + ((half * 4 + ko + m) & 7)) * 8];
            }
            #pragma unroll
            for (int j = 0; j < NJ; ++j) {
                int n = wc * (TN / 2) + j * 16 + ml;
                bfr[j] = *(const bf16x8*)&Bs[(n * 8 + ((half * 4 + ko + n) & 7)) * 8];
            }
            #pragma unroll
            for (int i = 0; i < MI; ++i)
                #pragma unroll
                for (int j = 0; j < NJ; ++j)
                    acc[i][j] = __builtin_amdgcn_mfma_f32_16x16x32_bf16(
                        af[i], bfr[j], acc[i][j], 0, 0, 0);
        }
        __syncthreads();
    }

    const int rq = lane >> 4;
    #pragma unroll
    for (int j = 0; j < NJ; ++j) {
        int n = n0 + wc * (TN / 2) + j * 16 + ml;
        float bv = bias ? bias[n] : 0.f;
        #pragma unroll
        for (int i = 0; i < MI; ++i) {
            int mb = m0 + wr * (TM / 2) + i * 16 + rq * 4;
            if (SPLIT && n >= 1024) {
                if (n < 1088) {
                    #pragma unroll
                    for (int r = 0; r < 4; ++r)
                        ((bf16*)Cv2)[(size_t)(mb + r) * 64 + (n - 1024)] =
                            __float2bfloat16(acc[i][j][r] + bv);
                }
            } else if (OT) {
                u16x4 pk;
                #pragma unroll
                for (int r = 0; r < 4; ++r)
                    pk[r] = f2b_bits(acc[i][j][r] + bv);
                *(u16x4*)((ushort_t*)Cv + (size_t)n * M + mb) = pk;
            } else {
                #pragma unroll
                for (int r = 0; r < 4; ++r) {
                    float v = acc[i][j][r] + bv;
                    if (OBF) ((bf16*)Cv)[(size_t)(mb + r) * N + n] = __float2bfloat16(v);
                    else     ((float*)Cv)[(size_t)(mb + r) * N + n] = v;
                }
            }
        }
    }
}

// ---------------------------------------------------------------------------
// Depthwise causal conv (width 4) + SiLU, channel-major in/out.
// Input xrbT [2048][4096]. Outputs xcT [1024][4096] + xc [4096][1024].
// ---------------------------------------------------------------------------
__global__ __launch_bounds__(256)
void conv_silu(const bf16* __restrict__ xrbT, const float* __restrict__ cw,
               const float* __restrict__ cb, bf16* __restrict__ xcT,
               bf16* __restrict__ xc)
{
    __shared__ ushort_t tile[64 * 72];   // 9 KB
    const int blk = blockIdx.x;
    const int ch0 = (blk & 15) * 64;
    const int T0b = (blk >> 4) * 64;
    const int lc = threadIdx.x >> 2, tg = threadIdx.x & 3;
    const int i = ch0 + lc;
    const int T0 = T0b + tg * 16;

    const ushort_t* base = (const ushort_t*)xrbT + (size_t)i * ROWS + T0;
    u16x8 m0 = *(const u16x8*)base;
    u16x8 m1 = *(const u16x8*)(base + 8);
    u16x8 pv = {0, 0, 0, 0, 0, 0, 0, 0};
    if ((T0 & (LL - 1)) != 0) pv = *(const u16x8*)(base - 8);

    float4 w = ((const float4*)cw)[i];
    float bs = cb[i];
    float xm3 = bits2f(pv[5]), xm2 = bits2f(pv[6]), xm1 = bits2f(pv[7]);
    u16x8 o0, o1;
    #pragma unroll
    for (int tt = 0; tt < 16; ++tt) {
        float x0 = bits2f(tt < 8 ? m0[tt] : m1[tt - 8]);
        float acc = bs;
        acc = fmaf(xm3, w.x, acc);
        acc = fmaf(xm2, w.y, acc);
        acc = fmaf(xm1, w.z, acc);
        acc = fmaf(x0,  w.w, acc);
        ushort_t ob = f2b_bits(acc / (1.f + __expf(-acc)));
        if (tt < 8) o0[tt] = ob; else o1[tt - 8] = ob;
        xm3 = xm2; xm2 = xm1; xm1 = x0;
    }
    ushort_t* dt = (ushort_t*)xcT + (size_t)i * ROWS + T0;
    *(u16x8*)dt = o0;
    *(u16x8*)(dt + 8) = o1;
    *(u16x8*)&tile[lc * 72 + tg * 16] = o0;
    *(u16x8*)&tile[lc * 72 + tg * 16 + 8] = o1;
    __syncthreads();
    const int lt = threadIdx.x >> 2, cg = threadIdx.x & 3;
    u16x8 q0, q1;
    #pragma unroll
    for (int j = 0; j < 8; ++j) q0[j] = tile[(cg * 16 + j) * 72 + lt];
    #pragma unroll
    for (int j = 8; j < 16; ++j) q1[j - 8] = tile[(cg * 16 + j) * 72 + lt];
    ushort_t* wp = (ushort_t*)xc + (size_t)(T0b + lt) * DI + ch0 + cg * 16;
    *(u16x8*)wp = q0;
    *(u16x8*)(wp + 8) = q1;
}

// ---------------------------------------------------------------------------
// FUSED chunked selective scan, transposed inputs, register-budgeted (<64).
// R11 lesson: 1-block/CU grid left VALU at 70% with occupancy 32% -> double
// the chunk parallelism: CT=8, NC=128; block = 8 ch x 128 chunks (1024 thr),
// grid 512 = 2 blocks/CU (2x64KB LDS = 128KB <= 160KB).
// ---------------------------------------------------------------------------
__global__ __launch_bounds__(1024)
void scan_fused(const bf16* __restrict__ xcT, const bf16* __restrict__ dT,
                const bf16* __restrict__ ssm, const bf16* __restrict__ xrbT,
                const float* __restrict__ A_log, const float* __restrict__ Dskip,
                bf16* __restrict__ ybf)
{
    __shared__ uint_t lsum[DS * NC * NCH];   // 16*128*8*4 = 64 KB

    const int tid = threadIdx.x;
    const int b = blockIdx.x >> 7;           // 512 blocks: 4 b x 128 groups
    const int ch0 = (blockIdx.x & 127) << 3;
    const int chl = tid & 7;
    const int c = tid >> 3;                  // chunk 0..127
    const int i = ch0 + chl;
    const size_t tb = (size_t)b * LL + c * CT;

    // A_log -> SGPRs (wave-uniform broadcast)
    float a[DS];
    #pragma unroll
    for (int s = 0; s < DS; ++s) {
        uint_t bits = (uint_t)__builtin_amdgcn_readfirstlane((int)__float_as_uint(A_log[s]));
        a[s] = __uint_as_float(bits);
    }

    const u16x8* dp = (const u16x8*)((const ushort_t*)dT + (size_t)i * ROWS + tb);
    const u16x8* up = (const u16x8*)((const ushort_t*)xcT + (size_t)i * ROWS + tb);
    const u16x8* rp = (const u16x8*)((const ushort_t*)xrbT + (size_t)(1024 + i) * ROWS + tb);

    float h[DS] = {};
    float p[DS];
    #pragma unroll
    for (int s = 0; s < DS; ++s) p[s] = 1.f;

    // ---- Pass A: chunk recurrence from h=0 (CT=8, one u16x8 per stream)
    {
        u16x8 dv8 = dp[0];
        u16x8 uv8 = up[0];
        #pragma unroll
        for (int t = 0; t < CT; ++t) {
            float dv = bits2f(dv8[t]);
            float uv = bits2f(uv8[t]);
            float du = dv * uv;
            const u16x8* sp = (const u16x8*)((const ushort_t*)ssm + (tb + t) * 64);
            u16x8 B0 = sp[0], B1 = sp[1];
            #pragma unroll
            for (int s = 0; s < DS; ++s) {
                float e = fminf(fmaxf(dv * a[s], -5.f), 5.f);
                float dA = __expf(e);
                float Bv = bits2f(s < 8 ? B0[s] : B1[s - 8]);
                h[s] = fmaf(dA, h[s], du * Bv);
                p[s] *= dA;
            }
        }
    }
    #pragma unroll
    for (int s = 0; s < DS; ++s)
        lsum[s * (NC * NCH) + tid] = (uint_t)f2b_bits(p[s]) | ((uint_t)f2b_bits(h[s]) << 16);
    __syncthreads();

    // ---- Combine (threads 0..127): (chl,s) serial over 128 chunks
    if (tid < NCH * DS) {
        int cl = tid & 7, s = tid >> 3;
        float hh = 0.f;
        for (int cc = 0; cc < NC; ++cc) {
            int off = s * (NC * NCH) + cc * NCH + cl;
            uint_t wrd = lsum[off];
            float pp = bits2f((ushort_t)(wrd & 0xFFFF));
            float qq = bits2f((ushort_t)(wrd >> 16));
            lsum[off] = (uint_t)f2b_bits(hh);      // h at chunk start
            hh = fmaf(pp, hh, qq);
        }
    }
    __syncthreads();

    #pragma unroll
    for (int s = 0; s < DS; ++s) h[s] = bits2f((ushort_t)lsum[s * (NC * NCH) + tid]);

    const float dsk = Dskip[i];

    // ---- Pass C: rerun from true h_start, emit gated y (row-major)
    {
        u16x8 dv8 = dp[0];
        u16x8 uv8 = up[0];
        u16x8 rv8 = rp[0];
        #pragma unroll
        for (int t = 0; t < CT; ++t) {
            float dv = bits2f(dv8[t]);
            float uv = bits2f(uv8[t]);
            float du = dv * uv;
            const u16x8* sp = (const u16x8*)((const ushort_t*)ssm + (tb + t) * 64);
            u16x8 B0 = sp[0], B1 = sp[1], C0 = sp[2], C1 = sp[3];
            float y = 0.f;
            #pragma unroll
            for (int s = 0; s < DS; ++s) {
                float e = fminf(fmaxf(dv * a[s], -5.f), 5.f);
                float dA = __expf(e);
                float Bv = bits2f(s < 8 ? B0[s] : B1[s - 8]);
                float Cc = bits2f(s < 8 ? C0[s] : C1[s - 8]);
                h[s] = fmaf(dA, h[s], du * Bv);
                y = fmaf(h[s], Cc, y);
            }
            float res = bits2f(rv8[t]);
            float g = res / (1.f + __expf(-res));
            ybf[(tb + t) * DI + i] = __float2bfloat16((y + uv * dsk) * g);
        }
    }
}

// ---------------------------------------------------------------------------
// r = outp(bf16) + clip(x_raw); LayerNorm over 512; dtype detected locally.
// ---------------------------------------------------------------------------
__global__ __launch_bounds__(256)
void ln_kernel(const bf16* __restrict__ outp, const void* __restrict__ xsrc,
               const void* __restrict__ wdt_probe,
               const float* __restrict__ gamma, const float* __restrict__ beta,
               void* __restrict__ out)
{
    const int isbf = detect_local((const ushort_t*)wdt_probe);
    const int row = blockIdx.x;
    const int tid = threadIdx.x;

    float r[2];
    float sum = 0.f, ss = 0.f;
    #pragma unroll
    for (int q = 0; q < 2; ++q) {
        int j = tid + q * 256;
        float xv = load_flag(xsrc, row * DM + j, isbf);
        xv = fminf(fmaxf(xv, -10.f), 10.f);
        float v = b2f(outp[(size_t)row * DM + j]) + xv;
        r[q] = v;
        sum += v;
        ss = fmaf(v, v, ss);
    }
    #pragma unroll
    for (int off = 32; off >= 1; off >>= 1) {
        sum += __shfl_down(sum, off);
        ss  += __shfl_down(ss, off);
    }
    __shared__ float s1[4], s2[4];
    __shared__ float stats[2];
    int wid = tid >> 6, lane = tid & 63;
    if (lane == 0) { s1[wid] = sum; s2[wid] = ss; }
    __syncthreads();
    if (tid == 0) {
        float S = s1[0] + s1[1] + s1[2] + s1[3];
        float Qq = s2[0] + s2[1] + s2[2] + s2[3];
        float mean = S / DM;
        float var = Qq / DM - mean * mean;
        stats[0] = mean;
        stats[1] = rsqrtf(var + 1e-5f);
    }
    __syncthreads();
    float mean = stats[0], rstd = stats[1];
    #pragma unroll
    for (int q = 0; q < 2; ++q) {
        int j = tid + q * 256;
        float v = (r[q] - mean) * rstd * gamma[j] + beta[j];
        size_t o = (size_t)row * DM + j;
        if (isbf) ((bf16*)out)[o] = __float2bfloat16(v);
        else      ((float*)out)[o] = v;
    }
}

// ---------------------------------------------------------------------------
extern "C" void kernel_launch(void* const* d_in, const int* in_sizes, int n_in,
                              void* d_out, int out_size, void* d_ws, size_t ws_size,
                              hipStream_t stream)
{
    float* W = (float*)d_ws;
    float* ccw  = W;                       // 4096
    float* ccb  = ccw  + 4096;             // 1024
    float* cAlg = ccb  + 1024;             // 16
    float* cDsk = cAlg + 16;               // 1024
    float* cgam = cDsk + 1024;             // 512
    float* cbet = cgam + 512;              // 512
    float* bdtx = cbet + 512;              // 1152
    bf16*  xbf  = (bf16*)(bdtx + 1152);    // 4096x512
    bf16*  xrbT = xbf  + 2097152;          // 2048x4096 (x_and_res transposed)
    bf16*  xcT  = xrbT + 8388608;          // 1024x4096 (xc transposed)
    bf16*  xc   = xcT  + 4194304;          // 4096x1024 (xc row-major)
    bf16*  ybf  = xc   + 4194304;          // 4096x1024
    bf16*  dT   = ybf  + 4194304;          // 1024x4096 (delta transposed)
    bf16*  ssm  = dT   + 4194304;          // 4096x64  (B|C|pad row-major)
    bf16*  outp = ssm  + 262144;           // 4096x512 bf16
    bf16*  WtIn = outp + 2097152;          // 2048x512
    bf16*  WtDtx= WtIn + 1048576;          // 1152x1024 (W_dt|W_x|0)
    bf16*  WtOut= WtDtx+ 1179648;          // 512x1024

    // 1) all prep (dtype detect per block, pack x, transposes, small params)
    prep_all<<<5057, 256, 0, stream>>>(
        d_in[0], d_in[1], d_in[5], d_in[4], d_in[9], d_in[2], d_in[3],
        d_in[7], d_in[8], d_in[10], d_in[11], d_in[6],
        xbf, WtIn, WtDtx, WtOut, ccw, ccb, cAlg, cDsk, cgam, cbet, bdtx);

    // 2) x_and_res^T = (clip(x) @ W_in)^T    [2048][4096] bf16
    gemm_mfma<64, 128, true, true, false><<<dim3(2048 / 128, ROWS / 64), 256, 0, stream>>>(
        xbf, WtIn, nullptr, xrbT, nullptr, ROWS, 2048, 512);

    // 3) depthwise causal conv + SiLU -> xcT + xc (dual layout)
    conv_silu<<<1024, 256, 0, stream>>>(xrbT, ccw, ccb, xcT, xc);

    // 4) fused delta^T | ssm GEMM: n<1024 -> dT[n][m], n in [1024,1088) -> ssm
    gemm_mfma<64, 128, true, true, true><<<dim3(NDTX / 128, ROWS / 64), 256, 0, stream>>>(
        xc, WtDtx, bdtx, dT, ssm, ROWS, NDTX, DI);

    // 5) fused chunked selective scan -> gated y row-major (512 blocks)
    scan_fused<<<512, 1024, 0, stream>>>(xcT, dT, ssm, xrbT, cAlg, cDsk, ybf);

    // 6) out_pre = y @ W_out                 [4096][512] bf16
    gemm_mfma<64, 64, true, false, false><<<dim3(DM / 64, ROWS / 64), 256, 0, stream>>>(
        ybf, WtOut, nullptr, outp, nullptr, ROWS, DM, DI);

    // 7) LayerNorm(out_pre + clip(x)) -> out (dtype detected locally)
    ln_kernel<<<ROWS, 256, 0, stream>>>(outp, d_in[0], d_in[5], cgam, cbet, d_out);
}

// Round 13
// 219.184 us; speedup vs baseline: 1.0022x; 1.0022x over previous
//
#include <hip/hip_runtime.h>
#include <hip/hip_bf16.h>

typedef __hip_bfloat16 bf16;
typedef unsigned short ushort_t;
typedef unsigned int uint_t;
typedef __attribute__((ext_vector_type(8))) __bf16 bf16x8;
typedef __attribute__((ext_vector_type(8))) ushort_t u16x8;
typedef __attribute__((ext_vector_type(4))) ushort_t u16x4;
typedef __attribute__((ext_vector_type(4))) float f32x4;

#define BB 4
#define LL 1024
#define DM 512
#define DS 16
#define DI 1024
#define ROWS 4096
#define NC 64       // chunks over time (R11 geometry — measured best)
#define CT 16       // steps per chunk
#define NDTX 1152   // padded N for fused [delta | ssm] GEMM (9*128)

#define CLP2 7.21347520f   // 5 * log2(e)

__device__ __forceinline__ float b2f(bf16 v) { return __bfloat162float(v); }

__device__ __forceinline__ float load_flag(const void* src, int i, int isbf)
{
    return isbf ? b2f(((const bf16*)src)[i]) : ((const float*)src)[i];
}

__device__ __forceinline__ ushort_t f2b_bits(float v)
{
    bf16 t = __float2bfloat16(v);
    return *(ushort_t*)&t;
}

__device__ __forceinline__ float bits2f(ushort_t u)
{
    uint_t w = ((uint_t)u) << 16;
    return __uint_as_float(w);
}

// Per-block dtype detection: sample 256 16-bit words of W_dt (scale 0.02).
__device__ __forceinline__ int detect_local(const ushort_t* wdt)
{
    __shared__ int bad;
    if (threadIdx.x == 0) bad = 0;
    __syncthreads();
    ushort_t u = wdt[threadIdx.x & 255];
    if (((u >> 7) & 0xFF) >= 127) atomicAdd(&bad, 1);
    __syncthreads();
    return (bad <= 8) ? 1 : 0;   // 1 = bf16 inputs
}

// ---------------------------------------------------------------------------
// ALL prep in one launch. Block ranges:
//   [0,2048):      pack_x  (x -> clipped bf16, 4 elems/thread)
//   [2048,4640):   weight transposes (LDS 32x32 tile)
//   [4640,5057):   small params + dtx bias + WtDtx pad-zero rows 1056..1151
// ---------------------------------------------------------------------------
__global__ __launch_bounds__(256)
void prep_all(const void* x, const void* Win, const void* Wdt, const void* Wx,
              const void* Wout, const void* cw, const void* cb, const void* Alog,
              const void* Dsk, const void* gam, const void* bet, const void* bdtin,
              bf16* __restrict__ xbf, bf16* __restrict__ WtIn,
              bf16* __restrict__ WtDtx, bf16* __restrict__ WtOut,
              float* __restrict__ ccw, float* __restrict__ ccb,
              float* __restrict__ cAlg, float* __restrict__ cDsk,
              float* __restrict__ cgam, float* __restrict__ cbet,
              float* __restrict__ bdtx)
{
    const int isbf = detect_local((const ushort_t*)Wdt);
    int blk = blockIdx.x;

    if (blk < 2048) {
        int idx = blk * 256 + threadIdx.x;
        float v[4];
        if (isbf) {
            uint2 raw = ((const uint2*)x)[idx];
            v[0] = __uint_as_float(raw.x << 16);
            v[1] = __uint_as_float(raw.x & 0xFFFF0000u);
            v[2] = __uint_as_float(raw.y << 16);
            v[3] = __uint_as_float(raw.y & 0xFFFF0000u);
        } else {
            float4 raw = ((const float4*)x)[idx];
            v[0] = raw.x; v[1] = raw.y; v[2] = raw.z; v[3] = raw.w;
        }
        uint_t b0, b1;
        b0 = f2b_bits(fminf(fmaxf(v[0], -10.f), 10.f))
           | ((uint_t)f2b_bits(fminf(fmaxf(v[1], -10.f), 10.f)) << 16);
        b1 = f2b_bits(fminf(fmaxf(v[2], -10.f), 10.f))
           | ((uint_t)f2b_bits(fminf(fmaxf(v[3], -10.f), 10.f)) << 16);
        uint2 ow; ow.x = b0; ow.y = b1;
        ((uint2*)xbf)[idx] = ow;
    } else if (blk < 4640) {
        int tb = blk - 2048;
        const void* src; bf16* dst; int K, Nsrc, tpr;
        if (tb < 1024)      { src = Win;  dst = WtIn;   K = 512;  Nsrc = 2048; tpr = 64; }
        else if (tb < 2048) { tb -= 1024; src = Wdt;  dst = WtDtx; K = 1024; Nsrc = 1024; tpr = 32; }
        else if (tb < 2080) { tb -= 2048; src = Wx;   dst = WtDtx + 1024 * 1024; K = 1024; Nsrc = 32; tpr = 1; }
        else                { tb -= 2080; src = Wout; dst = WtOut;  K = 1024; Nsrc = 512;  tpr = 16; }
        int k0 = (tb / tpr) * 32, n0 = (tb % tpr) * 32;

        __shared__ float tile[32][33];
        int tx = threadIdx.x & 31, ty = threadIdx.x >> 5;
        #pragma unroll
        for (int j = 0; j < 4; ++j)
            tile[ty + 8 * j][tx] = load_flag(src, (k0 + ty + 8 * j) * Nsrc + n0 + tx, isbf);
        __syncthreads();
        #pragma unroll
        for (int j = 0; j < 4; ++j)
            dst[(size_t)(n0 + ty + 8 * j) * K + k0 + tx] = __float2bfloat16(tile[tx][ty + 8 * j]);
    } else {
        int i = (blk - 4640) * 256 + threadIdx.x;
        if (i < 4096)        ccw[i] = load_flag(cw, i, isbf);
        else if (i < 5120)   ccb[i - 4096] = load_flag(cb, i - 4096, isbf);
        else if (i < 5136)   cAlg[i - 5120] = load_flag(Alog, i - 5120, isbf);
        else if (i < 6160)   cDsk[i - 5136] = load_flag(Dsk, i - 5136, isbf);
        else if (i < 6672)   cgam[i - 6160] = load_flag(gam, i - 6160, isbf);
        else if (i < 7184)   cbet[i - 6672] = load_flag(bet, i - 6672, isbf);
        else if (i < 8336) {
            int j = i - 7184;
            bdtx[j] = (j < DI) ? load_flag(bdtin, j, isbf) : 0.f;
        } else if (i < 106640) {
            (WtDtx + 1056 * 1024)[i - 8336] = __float2bfloat16(0.f);
        }
    }
}

// ---------------------------------------------------------------------------
// MFMA bf16 GEMM: C = A[M][K] * Bt[N][K]^T (+bias).
// TM x TN tile, 4 waves (2x2), 16x16x32 frags, BK=64, global_load_lds
// width-16 with XOR 8-chunk swizzle.
// OT: store transposed DT[n][m] bf16 (u16x4). OBF: bf16 row-major.
// SPLIT: cols n in [1024,1088) stored row-major FP32 to Cv2 (stride 64,
// col n-1024); n >= 1088 dropped. Used for fused delta|ssm GEMM.
// ---------------------------------------------------------------------------
__device__ __forceinline__ void gload16(const bf16* g, ushort_t* l)
{
    __builtin_amdgcn_global_load_lds(
        (const __attribute__((address_space(1))) void*)g,
        (__attribute__((address_space(3))) void*)l, 16, 0, 0);
}

template <int TM, int TN, bool OBF, bool OT, bool SPLIT>
__global__ __launch_bounds__(256)
void gemm_mfma(const bf16* __restrict__ A, const bf16* __restrict__ Bt,
               const float* __restrict__ bias, void* __restrict__ Cv,
               void* __restrict__ Cv2, int M, int N, int K)
{
    constexpr int MI = TM / 32, NJ = TN / 32;
    constexpr int NQA = TM * 8 / 256;
    constexpr int NQB = TN * 8 / 256;
    __shared__ ushort_t As[TM * 64];
    __shared__ ushort_t Bs[TN * 64];

    const int tid = threadIdx.x;
    const int lane = tid & 63;
    const int w = tid >> 6;
    const int wr = w >> 1, wc = w & 1;
    const int m0 = blockIdx.y * TM;
    const int n0 = blockIdx.x * TN;

    const bf16* gA[NQA]; ushort_t* lA[NQA];
    #pragma unroll
    for (int q = 0; q < NQA; ++q) {
        int p = q * 256 + tid;
        int row = p >> 3, kc = ((p & 7) - row) & 7;
        gA[q] = A + (size_t)(m0 + row) * K + kc * 8;
        lA[q] = &As[(q * 256 + w * 64) * 8];
    }
    const bf16* gB[NQB]; ushort_t* lB[NQB];
    #pragma unroll
    for (int q = 0; q < NQB; ++q) {
        int p = q * 256 + tid;
        int row = p >> 3, kc = ((p & 7) - row) & 7;
        gB[q] = Bt + (size_t)(n0 + row) * K + kc * 8;
        lB[q] = &Bs[(q * 256 + w * 64) * 8];
    }

    f32x4 acc[MI][NJ];
    #pragma unroll
    for (int i = 0; i < MI; ++i)
        #pragma unroll
        for (int j = 0; j < NJ; ++j)
            acc[i][j] = (f32x4){0.f, 0.f, 0.f, 0.f};

    const int ko = lane >> 4;
    const int ml = lane & 15;

    for (int k0 = 0; k0 < K; k0 += 64) {
        #pragma unroll
        for (int q = 0; q < NQA; ++q) gload16(gA[q] + k0, lA[q]);
        #pragma unroll
        for (int q = 0; q < NQB; ++q) gload16(gB[q] + k0, lB[q]);
        __syncthreads();

        #pragma unroll
        for (int half = 0; half < 2; ++half) {
            bf16x8 af[MI], bfr[NJ];
            #pragma unroll
            for (int i = 0; i < MI; ++i) {
                int m = wr * (TM / 2) + i * 16 + ml;
                af[i] = *(const bf16x8*)&As[(m * 8 + ((half * 4 + ko + m) & 7)) * 8];
            }
            #pragma unroll
            for (int j = 0; j < NJ; ++j) {
                int n = wc * (TN / 2) + j * 16 + ml;
                bfr[j] = *(const bf16x8*)&Bs[(n * 8 + ((half * 4 + ko + n) & 7)) * 8];
            }
            #pragma unroll
            for (int i = 0; i < MI; ++i)
                #pragma unroll
                for (int j = 0; j < NJ; ++j)
                    acc[i][j] = __builtin_amdgcn_mfma_f32_16x16x32_bf16(
                        af[i], bfr[j], acc[i][j], 0, 0, 0);
        }
        __syncthreads();
    }

    const int rq = lane >> 4;
    #pragma unroll
    for (int j = 0; j < NJ; ++j) {
        int n = n0 + wc * (TN / 2) + j * 16 + ml;
        float bv = bias ? bias[n] : 0.f;
        #pragma unroll
        for (int i = 0; i < MI; ++i) {
            int mb = m0 + wr * (TM / 2) + i * 16 + rq * 4;
            if (SPLIT && n >= 1024) {
                if (n < 1088) {
                    #pragma unroll
                    for (int r = 0; r < 4; ++r)
                        ((float*)Cv2)[(size_t)(mb + r) * 64 + (n - 1024)] =
                            acc[i][j][r] + bv;
                }
            } else if (OT) {
                u16x4 pk;
                #pragma unroll
                for (int r = 0; r < 4; ++r)
                    pk[r] = f2b_bits(acc[i][j][r] + bv);
                *(u16x4*)((ushort_t*)Cv + (size_t)n * M + mb) = pk;
            } else {
                #pragma unroll
                for (int r = 0; r < 4; ++r) {
                    float v = acc[i][j][r] + bv;
                    if (OBF) ((bf16*)Cv)[(size_t)(mb + r) * N + n] = __float2bfloat16(v);
                    else     ((float*)Cv)[(size_t)(mb + r) * N + n] = v;
                }
            }
        }
    }
}

// ---------------------------------------------------------------------------
// Depthwise causal conv (width 4) + SiLU, channel-major in/out.
// Input xrbT [2048][4096]. Outputs xcT [1024][4096] + xc [4096][1024].
// ---------------------------------------------------------------------------
__global__ __launch_bounds__(256)
void conv_silu(const bf16* __restrict__ xrbT, const float* __restrict__ cw,
               const float* __restrict__ cb, bf16* __restrict__ xcT,
               bf16* __restrict__ xc)
{
    __shared__ ushort_t tile[64 * 72];   // 9 KB
    const int blk = blockIdx.x;
    const int ch0 = (blk & 15) * 64;
    const int T0b = (blk >> 4) * 64;
    const int lc = threadIdx.x >> 2, tg = threadIdx.x & 3;
    const int i = ch0 + lc;
    const int T0 = T0b + tg * 16;

    const ushort_t* base = (const ushort_t*)xrbT + (size_t)i * ROWS + T0;
    u16x8 m0 = *(const u16x8*)base;
    u16x8 m1 = *(const u16x8*)(base + 8);
    u16x8 pv = {0, 0, 0, 0, 0, 0, 0, 0};
    if ((T0 & (LL - 1)) != 0) pv = *(const u16x8*)(base - 8);

    float4 w = ((const float4*)cw)[i];
    float bs = cb[i];
    float xm3 = bits2f(pv[5]), xm2 = bits2f(pv[6]), xm1 = bits2f(pv[7]);
    u16x8 o0, o1;
    #pragma unroll
    for (int tt = 0; tt < 16; ++tt) {
        float x0 = bits2f(tt < 8 ? m0[tt] : m1[tt - 8]);
        float acc = bs;
        acc = fmaf(xm3, w.x, acc);
        acc = fmaf(xm2, w.y, acc);
        acc = fmaf(xm1, w.z, acc);
        acc = fmaf(x0,  w.w, acc);
        ushort_t ob = f2b_bits(acc / (1.f + __expf(-acc)));
        if (tt < 8) o0[tt] = ob; else o1[tt - 8] = ob;
        xm3 = xm2; xm2 = xm1; xm1 = x0;
    }
    ushort_t* dt = (ushort_t*)xcT + (size_t)i * ROWS + T0;
    *(u16x8*)dt = o0;
    *(u16x8*)(dt + 8) = o1;
    *(u16x8*)&tile[lc * 72 + tg * 16] = o0;
    *(u16x8*)&tile[lc * 72 + tg * 16 + 8] = o1;
    __syncthreads();
    const int lt = threadIdx.x >> 2, cg = threadIdx.x & 3;
    u16x8 q0, q1;
    #pragma unroll
    for (int j = 0; j < 8; ++j) q0[j] = tile[(cg * 16 + j) * 72 + lt];
    #pragma unroll
    for (int j = 8; j < 16; ++j) q1[j - 8] = tile[(cg * 16 + j) * 72 + lt];
    ushort_t* wp = (ushort_t*)xc + (size_t)(T0b + lt) * DI + ch0 + cg * 16;
    *(u16x8*)wp = q0;
    *(u16x8*)(wp + 8) = q1;
}

// ---------------------------------------------------------------------------
// FUSED chunked selective scan. R11 geometry (measured best: 16 ch x 64
// chunks, 256 blocks). VALU-slot reductions (R12 lesson: VALU-bound at 67%):
//  - ssm B/C read as FP32 float4 quads (kills 48 bf16-unpack lshl per elem-t)
//  - exp2-domain: a2[s]=A_log[s]*log2e in SGPRs, clamp +-5*log2e, exp2f
//  - quads loaded per 4-s group to bound live VGPRs (<64 cap, R9/R11 lesson)
// ---------------------------------------------------------------------------
__global__ __launch_bounds__(1024)
void scan_fused(const bf16* __restrict__ xcT, const bf16* __restrict__ dT,
                const float* __restrict__ ssm, const bf16* __restrict__ xrbT,
                const float* __restrict__ A_log, const float* __restrict__ Dskip,
                bf16* __restrict__ ybf)
{
    __shared__ uint_t lsum[DS * NC * 16];   // 64 KB

    const int tid = threadIdx.x;
    const int b = blockIdx.x >> 6;
    const int ch0 = (blockIdx.x & 63) << 4;
    const int chl = tid & 15;
    const int c = tid >> 4;                  // chunk 0..63
    const int i = ch0 + chl;
    const size_t tb = (size_t)b * LL + c * CT;

    // a2[s] = A_log[s] * log2(e), wave-uniform in SGPRs
    float a2[DS];
    #pragma unroll
    for (int s = 0; s < DS; ++s) {
        uint_t bits = (uint_t)__builtin_amdgcn_readfirstlane((int)__float_as_uint(A_log[s]));
        a2[s] = __uint_as_float(bits) * 1.44269504f;
    }

    const u16x8* dp = (const u16x8*)((const ushort_t*)dT + (size_t)i * ROWS + tb);
    const u16x8* up = (const u16x8*)((const ushort_t*)xcT + (size_t)i * ROWS + tb);
    const u16x8* rp = (const u16x8*)((const ushort_t*)xrbT + (size_t)(1024 + i) * ROWS + tb);

    float h[DS] = {};
    float p[DS];
    #pragma unroll
    for (int s = 0; s < DS; ++s) p[s] = 1.f;

    // ---- Pass A: chunk recurrence from h=0
    #pragma unroll
    for (int half = 0; half < 2; ++half) {
        u16x8 dv8 = dp[half];
        u16x8 uv8 = up[half];
        #pragma unroll
        for (int t = 0; t < 8; ++t) {
            float dv = bits2f(dv8[t]);
            float uv = bits2f(uv8[t]);
            float du = dv * uv;
            const f32x4* sv = (const f32x4*)(ssm + (tb + half * 8 + t) * 64);
            #pragma unroll
            for (int g = 0; g < 4; ++g) {
                f32x4 Bq = sv[g];
                #pragma unroll
                for (int q = 0; q < 4; ++q) {
                    int s = g * 4 + q;
                    float e = fminf(fmaxf(dv * a2[s], -CLP2), CLP2);
                    float dA = exp2f(e);
                    h[s] = fmaf(dA, h[s], du * Bq[q]);
                    p[s] *= dA;
                }
            }
        }
    }
    #pragma unroll
    for (int s = 0; s < DS; ++s)
        lsum[s * 1024 + tid] = (uint_t)f2b_bits(p[s]) | ((uint_t)f2b_bits(h[s]) << 16);
    __syncthreads();

    // ---- Combine (threads 0..255): (chl,s) serial over 64 chunks
    if (tid < 256) {
        int cl = tid & 15, s = tid >> 4;
        float hh = 0.f;
        for (int cc = 0; cc < NC; ++cc) {
            int off = s * 1024 + cc * 16 + cl;
            uint_t wrd = lsum[off];
            float pp = bits2f((ushort_t)(wrd & 0xFFFF));
            float qq = bits2f((ushort_t)(wrd >> 16));
            lsum[off] = (uint_t)f2b_bits(hh);      // h at chunk start
            hh = fmaf(pp, hh, qq);
        }
    }
    __syncthreads();

    #pragma unroll
    for (int s = 0; s < DS; ++s) h[s] = bits2f((ushort_t)lsum[s * 1024 + tid]);

    const float dsk = Dskip[i];

    // ---- Pass C: rerun from true h_start, emit gated y (row-major)
    #pragma unroll
    for (int half = 0; half < 2; ++half) {
        u16x8 dv8 = dp[half];
        u16x8 uv8 = up[half];
        u16x8 rv8 = rp[half];
        #pragma unroll
        for (int t = 0; t < 8; ++t) {
            float dv = bits2f(dv8[t]);
            float uv = bits2f(uv8[t]);
            float du = dv * uv;
            const f32x4* sv = (const f32x4*)(ssm + (tb + half * 8 + t) * 64);
            float y = 0.f;
            #pragma unroll
            for (int g = 0; g < 4; ++g) {
                f32x4 Bq = sv[g];
                f32x4 Cq = sv[4 + g];
                #pragma unroll
                for (int q = 0; q < 4; ++q) {
                    int s = g * 4 + q;
                    float e = fminf(fmaxf(dv * a2[s], -CLP2), CLP2);
                    float dA = exp2f(e);
                    h[s] = fmaf(dA, h[s], du * Bq[q]);
                    y = fmaf(h[s], Cq[q], y);
                }
            }
            float res = bits2f(rv8[t]);
            float g2 = res / (1.f + __expf(-res));
            ybf[(tb + half * 8 + t) * DI + i] = __float2bfloat16((y + uv * dsk) * g2);
        }
    }
}

// ---------------------------------------------------------------------------
// r = outp(bf16) + clip(x_raw); LayerNorm over 512; dtype detected locally.
// ---------------------------------------------------------------------------
__global__ __launch_bounds__(256)
void ln_kernel(const bf16* __restrict__ outp, const void* __restrict__ xsrc,
               const void* __restrict__ wdt_probe,
               const float* __restrict__ gamma, const float* __restrict__ beta,
               void* __restrict__ out)
{
    const int isbf = detect_local((const ushort_t*)wdt_probe);
    const int row = blockIdx.x;
    const int tid = threadIdx.x;

    float r[2];
    float sum = 0.f, ss = 0.f;
    #pragma unroll
    for (int q = 0; q < 2; ++q) {
        int j = tid + q * 256;
        float xv = load_flag(xsrc, row * DM + j, isbf);
        xv = fminf(fmaxf(xv, -10.f), 10.f);
        float v = b2f(outp[(size_t)row * DM + j]) + xv;
        r[q] = v;
        sum += v;
        ss = fmaf(v, v, ss);
    }
    #pragma unroll
    for (int off = 32; off >= 1; off >>= 1) {
        sum += __shfl_down(sum, off);
        ss  += __shfl_down(ss, off);
    }
    __shared__ float s1[4], s2[4];
    __shared__ float stats[2];
    int wid = tid >> 6, lane = tid & 63;
    if (lane == 0) { s1[wid] = sum; s2[wid] = ss; }
    __syncthreads();
    if (tid == 0) {
        float S = s1[0] + s1[1] + s1[2] + s1[3];
        float Qq = s2[0] + s2[1] + s2[2] + s2[3];
        float mean = S / DM;
        float var = Qq / DM - mean * mean;
        stats[0] = mean;
        stats[1] = rsqrtf(var + 1e-5f);
    }
    __syncthreads();
    float mean = stats[0], rstd = stats[1];
    #pragma unroll
    for (int q = 0; q < 2; ++q) {
        int j = tid + q * 256;
        float v = (r[q] - mean) * rstd * gamma[j] + beta[j];
        size_t o = (size_t)row * DM + j;
        if (isbf) ((bf16*)out)[o] = __float2bfloat16(v);
        else      ((float*)out)[o] = v;
    }
}

// ---------------------------------------------------------------------------
extern "C" void kernel_launch(void* const* d_in, const int* in_sizes, int n_in,
                              void* d_out, int out_size, void* d_ws, size_t ws_size,
                              hipStream_t stream)
{
    float* W = (float*)d_ws;
    float* ccw  = W;                       // 4096
    float* ccb  = ccw  + 4096;             // 1024
    float* cAlg = ccb  + 1024;             // 16
    float* cDsk = cAlg + 16;               // 1024
    float* cgam = cDsk + 1024;             // 512
    float* cbet = cgam + 512;              // 512
    float* bdtx = cbet + 512;              // 1152
    float* ssm  = bdtx + 1152;             // 4096x64 FP32 (B|C|pad row-major)
    bf16*  xbf  = (bf16*)(ssm + 262144);   // 4096x512
    bf16*  xrbT = xbf  + 2097152;          // 2048x4096 (x_and_res transposed)
    bf16*  xcT  = xrbT + 8388608;          // 1024x4096 (xc transposed)
    bf16*  xc   = xcT  + 4194304;          // 4096x1024 (xc row-major)
    bf16*  ybf  = xc   + 4194304;          // 4096x1024
    bf16*  dT   = ybf  + 4194304;          // 1024x4096 (delta transposed)
    bf16*  outp = dT   + 4194304;          // 4096x512 bf16
    bf16*  WtIn = outp + 2097152;          // 2048x512
    bf16*  WtDtx= WtIn + 1048576;          // 1152x1024 (W_dt|W_x|0)
    bf16*  WtOut= WtDtx+ 1179648;          // 512x1024

    // 1) all prep (dtype detect per block, pack x, transposes, small params)
    prep_all<<<5057, 256, 0, stream>>>(
        d_in[0], d_in[1], d_in[5], d_in[4], d_in[9], d_in[2], d_in[3],
        d_in[7], d_in[8], d_in[10], d_in[11], d_in[6],
        xbf, WtIn, WtDtx, WtOut, ccw, ccb, cAlg, cDsk, cgam, cbet, bdtx);

    // 2) x_and_res^T = (clip(x) @ W_in)^T    [2048][4096] bf16, 128x128 tile
    gemm_mfma<128, 128, true, true, false><<<dim3(2048 / 128, ROWS / 128), 256, 0, stream>>>(
        xbf, WtIn, nullptr, xrbT, nullptr, ROWS, 2048, 512);

    // 3) depthwise causal conv + SiLU -> xcT + xc (dual layout)
    conv_silu<<<1024, 256, 0, stream>>>(xrbT, ccw, ccb, xcT, xc);

    // 4) fused delta^T | ssm GEMM: n<1024 -> dT[n][m] bf16; [1024,1088) -> ssm fp32
    gemm_mfma<64, 128, true, true, true><<<dim3(NDTX / 128, ROWS / 64), 256, 0, stream>>>(
        xc, WtDtx, bdtx, dT, ssm, ROWS, NDTX, DI);

    // 5) fused chunked selective scan -> gated y row-major (256 blocks)
    scan_fused<<<256, 1024, 0, stream>>>(xcT, dT, ssm, xrbT, cAlg, cDsk, ybf);

    // 6) out_pre = y @ W_out                 [4096][512] bf16
    gemm_mfma<64, 64, true, false, false><<<dim3(DM / 64, ROWS / 64), 256, 0, stream>>>(
        ybf, WtOut, nullptr, outp, nullptr, ROWS, DM, DI);

    // 7) LayerNorm(out_pre + clip(x)) -> out (dtype detected locally)
    ln_kernel<<<ROWS, 256, 0, stream>>>(outp, d_in[0], d_in[5], cgam, cbet, d_out);
}

// Round 14
// 206.007 us; speedup vs baseline: 1.0663x; 1.0640x over previous
//
#include <hip/hip_runtime.h>
#include <hip/hip_bf16.h>

typedef __hip_bfloat16 bf16;
typedef unsigned short ushort_t;
typedef unsigned int uint_t;
typedef __attribute__((ext_vector_type(8))) __bf16 bf16x8;
typedef __attribute__((ext_vector_type(8))) ushort_t u16x8;
typedef __attribute__((ext_vector_type(4))) ushort_t u16x4;
typedef __attribute__((ext_vector_type(4))) float f32x4;
typedef __attribute__((ext_vector_type(2))) float f32x2;

#define BB 4
#define LL 1024
#define DM 512
#define DS 16
#define DI 1024
#define ROWS 4096
#define NC 64       // chunks over time (R11 geometry — measured best)
#define CT 16       // steps per chunk
#define NDTX 1152   // padded N for fused [delta | ssm] GEMM (9*128)

__device__ __forceinline__ float b2f(bf16 v) { return __bfloat162float(v); }

__device__ __forceinline__ float load_flag(const void* src, int i, int isbf)
{
    return isbf ? b2f(((const bf16*)src)[i]) : ((const float*)src)[i];
}

__device__ __forceinline__ ushort_t f2b_bits(float v)
{
    bf16 t = __float2bfloat16(v);
    return *(ushort_t*)&t;
}

__device__ __forceinline__ float bits2f(ushort_t u)
{
    uint_t w = ((uint_t)u) << 16;
    return __uint_as_float(w);
}

// Per-block dtype detection: sample 256 16-bit words of W_dt (scale 0.02).
__device__ __forceinline__ int detect_local(const ushort_t* wdt)
{
    __shared__ int bad;
    if (threadIdx.x == 0) bad = 0;
    __syncthreads();
    ushort_t u = wdt[threadIdx.x & 255];
    if (((u >> 7) & 0xFF) >= 127) atomicAdd(&bad, 1);
    __syncthreads();
    return (bad <= 8) ? 1 : 0;   // 1 = bf16 inputs
}

// ---------------------------------------------------------------------------
// ALL prep in one launch. Block ranges:
//   [0,2048):      pack_x  (x -> clipped bf16, 4 elems/thread)
//   [2048,4640):   weight transposes (LDS 32x32 tile)
//   [4640,5057):   small params + dtx bias + WtDtx pad-zero rows 1056..1151
// ---------------------------------------------------------------------------
__global__ __launch_bounds__(256)
void prep_all(const void* x, const void* Win, const void* Wdt, const void* Wx,
              const void* Wout, const void* cw, const void* cb, const void* Alog,
              const void* Dsk, const void* gam, const void* bet, const void* bdtin,
              bf16* __restrict__ xbf, bf16* __restrict__ WtIn,
              bf16* __restrict__ WtDtx, bf16* __restrict__ WtOut,
              float* __restrict__ ccw, float* __restrict__ ccb,
              float* __restrict__ cAlg, float* __restrict__ cDsk,
              float* __restrict__ cgam, float* __restrict__ cbet,
              float* __restrict__ bdtx)
{
    const int isbf = detect_local((const ushort_t*)Wdt);
    int blk = blockIdx.x;

    if (blk < 2048) {
        int idx = blk * 256 + threadIdx.x;
        float v[4];
        if (isbf) {
            uint2 raw = ((const uint2*)x)[idx];
            v[0] = __uint_as_float(raw.x << 16);
            v[1] = __uint_as_float(raw.x & 0xFFFF0000u);
            v[2] = __uint_as_float(raw.y << 16);
            v[3] = __uint_as_float(raw.y & 0xFFFF0000u);
        } else {
            float4 raw = ((const float4*)x)[idx];
            v[0] = raw.x; v[1] = raw.y; v[2] = raw.z; v[3] = raw.w;
        }
        uint_t b0, b1;
        b0 = f2b_bits(fminf(fmaxf(v[0], -10.f), 10.f))
           | ((uint_t)f2b_bits(fminf(fmaxf(v[1], -10.f), 10.f)) << 16);
        b1 = f2b_bits(fminf(fmaxf(v[2], -10.f), 10.f))
           | ((uint_t)f2b_bits(fminf(fmaxf(v[3], -10.f), 10.f)) << 16);
        uint2 ow; ow.x = b0; ow.y = b1;
        ((uint2*)xbf)[idx] = ow;
    } else if (blk < 4640) {
        int tb = blk - 2048;
        const void* src; bf16* dst; int K, Nsrc, tpr;
        if (tb < 1024)      { src = Win;  dst = WtIn;   K = 512;  Nsrc = 2048; tpr = 64; }
        else if (tb < 2048) { tb -= 1024; src = Wdt;  dst = WtDtx; K = 1024; Nsrc = 1024; tpr = 32; }
        else if (tb < 2080) { tb -= 2048; src = Wx;   dst = WtDtx + 1024 * 1024; K = 1024; Nsrc = 32; tpr = 1; }
        else                { tb -= 2080; src = Wout; dst = WtOut;  K = 1024; Nsrc = 512;  tpr = 16; }
        int k0 = (tb / tpr) * 32, n0 = (tb % tpr) * 32;

        __shared__ float tile[32][33];
        int tx = threadIdx.x & 31, ty = threadIdx.x >> 5;
        #pragma unroll
        for (int j = 0; j < 4; ++j)
            tile[ty + 8 * j][tx] = load_flag(src, (k0 + ty + 8 * j) * Nsrc + n0 + tx, isbf);
        __syncthreads();
        #pragma unroll
        for (int j = 0; j < 4; ++j)
            dst[(size_t)(n0 + ty + 8 * j) * K + k0 + tx] = __float2bfloat16(tile[tx][ty + 8 * j]);
    } else {
        int i = (blk - 4640) * 256 + threadIdx.x;
        if (i < 4096)        ccw[i] = load_flag(cw, i, isbf);
        else if (i < 5120)   ccb[i - 4096] = load_flag(cb, i - 4096, isbf);
        else if (i < 5136)   cAlg[i - 5120] = load_flag(Alog, i - 5120, isbf);
        else if (i < 6160)   cDsk[i - 5136] = load_flag(Dsk, i - 5136, isbf);
        else if (i < 6672)   cgam[i - 6160] = load_flag(gam, i - 6160, isbf);
        else if (i < 7184)   cbet[i - 6672] = load_flag(bet, i - 6672, isbf);
        else if (i < 8336) {
            int j = i - 7184;
            bdtx[j] = (j < DI) ? load_flag(bdtin, j, isbf) : 0.f;
        } else if (i < 106640) {
            (WtDtx + 1056 * 1024)[i - 8336] = __float2bfloat16(0.f);
        }
    }
}

// ---------------------------------------------------------------------------
// MFMA bf16 GEMM: C = A[M][K] * Bt[N][K]^T (+bias).
// TM x TN tile, 4 waves (2x2), 16x16x32 frags, BK=64, global_load_lds
// width-16 with XOR 8-chunk swizzle.
// OT: store transposed DT[n][m] bf16 (u16x4). OBF: bf16 row-major.
// SPLIT: cols n in [1024,1088) stored row-major BF16 to Cv2 (stride 64,
// col n-1024); n >= 1088 dropped. Used for fused delta|ssm GEMM.
// ---------------------------------------------------------------------------
__device__ __forceinline__ void gload16(const bf16* g, ushort_t* l)
{
    __builtin_amdgcn_global_load_lds(
        (const __attribute__((address_space(1))) void*)g,
        (__attribute__((address_space(3))) void*)l, 16, 0, 0);
}

template <int TM, int TN, bool OBF, bool OT, bool SPLIT>
__global__ __launch_bounds__(256)
void gemm_mfma(const bf16* __restrict__ A, const bf16* __restrict__ Bt,
               const float* __restrict__ bias, void* __restrict__ Cv,
               void* __restrict__ Cv2, int M, int N, int K)
{
    constexpr int MI = TM / 32, NJ = TN / 32;
    constexpr int NQA = TM * 8 / 256;
    constexpr int NQB = TN * 8 / 256;
    __shared__ ushort_t As[TM * 64];
    __shared__ ushort_t Bs[TN * 64];

    const int tid = threadIdx.x;
    const int lane = tid & 63;
    const int w = tid >> 6;
    const int wr = w >> 1, wc = w & 1;
    const int m0 = blockIdx.y * TM;
    const int n0 = blockIdx.x * TN;

    const bf16* gA[NQA]; ushort_t* lA[NQA];
    #pragma unroll
    for (int q = 0; q < NQA; ++q) {
        int p = q * 256 + tid;
        int row = p >> 3, kc = ((p & 7) - row) & 7;
        gA[q] = A + (size_t)(m0 + row) * K + kc * 8;
        lA[q] = &As[(q * 256 + w * 64) * 8];
    }
    const bf16* gB[NQB]; ushort_t* lB[NQB];
    #pragma unroll
    for (int q = 0; q < NQB; ++q) {
        int p = q * 256 + tid;
        int row = p >> 3, kc = ((p & 7) - row) & 7;
        gB[q] = Bt + (size_t)(n0 + row) * K + kc * 8;
        lB[q] = &Bs[(q * 256 + w * 64) * 8];
    }

    f32x4 acc[MI][NJ];
    #pragma unroll
    for (int i = 0; i < MI; ++i)
        #pragma unroll
        for (int j = 0; j < NJ; ++j)
            acc[i][j] = (f32x4){0.f, 0.f, 0.f, 0.f};

    const int ko = lane >> 4;
    const int ml = lane & 15;

    for (int k0 = 0; k0 < K; k0 += 64) {
        #pragma unroll
        for (int q = 0; q < NQA; ++q) gload16(gA[q] + k0, lA[q]);
        #pragma unroll
        for (int q = 0; q < NQB; ++q) gload16(gB[q] + k0, lB[q]);
        __syncthreads();

        #pragma unroll
        for (int half = 0; half < 2; ++half) {
            bf16x8 af[MI], bfr[NJ];
            #pragma unroll
            for (int i = 0; i < MI; ++i) {
                int m = wr * (TM / 2) + i * 16 + ml;
                af[i] = *(const bf16x8*)&As[(m * 8 + ((half * 4 + ko + m) & 7)) * 8];
            }
            #pragma unroll
            for (int j = 0; j < NJ; ++j) {
                int n = wc * (TN / 2) + j * 16 + ml;
                bfr[j] = *(const bf16x8*)&Bs[(n * 8 + ((half * 4 + ko + n) & 7)) * 8];
            }
            #pragma unroll
            for (int i = 0; i < MI; ++i)
                #pragma unroll
                for (int j = 0; j < NJ; ++j)
                    acc[i][j] = __builtin_amdgcn_mfma_f32_16x16x32_bf16(
                        af[i], bfr[j], acc[i][j], 0, 0, 0);
        }
        __syncthreads();
    }

    const int rq = lane >> 4;
    #pragma unroll
    for (int j = 0; j < NJ; ++j) {
        int n = n0 + wc * (TN / 2) + j * 16 + ml;
        float bv = bias ? bias[n] : 0.f;
        #pragma unroll
        for (int i = 0; i < MI; ++i) {
            int mb = m0 + wr * (TM / 2) + i * 16 + rq * 4;
            if (SPLIT && n >= 1024) {
                if (n < 1088) {
                    #pragma unroll
                    for (int r = 0; r < 4; ++r)
                        ((bf16*)Cv2)[(size_t)(mb + r) * 64 + (n - 1024)] =
                            __float2bfloat16(acc[i][j][r] + bv);
                }
            } else if (OT) {
                u16x4 pk;
                #pragma unroll
                for (int r = 0; r < 4; ++r)
                    pk[r] = f2b_bits(acc[i][j][r] + bv);
                *(u16x4*)((ushort_t*)Cv + (size_t)n * M + mb) = pk;
            } else {
                #pragma unroll
                for (int r = 0; r < 4; ++r) {
                    float v = acc[i][j][r] + bv;
                    if (OBF) ((bf16*)Cv)[(size_t)(mb + r) * N + n] = __float2bfloat16(v);
                    else     ((float*)Cv)[(size_t)(mb + r) * N + n] = v;
                }
            }
        }
    }
}

// ---------------------------------------------------------------------------
// Depthwise causal conv (width 4) + SiLU, channel-major in/out.
// Input xrbT [2048][4096]. Outputs xcT [1024][4096] + xc [4096][1024].
// ---------------------------------------------------------------------------
__global__ __launch_bounds__(256)
void conv_silu(const bf16* __restrict__ xrbT, const float* __restrict__ cw,
               const float* __restrict__ cb, bf16* __restrict__ xcT,
               bf16* __restrict__ xc)
{
    __shared__ ushort_t tile[64 * 72];   // 9 KB
    const int blk = blockIdx.x;
    const int ch0 = (blk & 15) * 64;
    const int T0b = (blk >> 4) * 64;
    const int lc = threadIdx.x >> 2, tg = threadIdx.x & 3;
    const int i = ch0 + lc;
    const int T0 = T0b + tg * 16;

    const ushort_t* base = (const ushort_t*)xrbT + (size_t)i * ROWS + T0;
    u16x8 m0 = *(const u16x8*)base;
    u16x8 m1 = *(const u16x8*)(base + 8);
    u16x8 pv = {0, 0, 0, 0, 0, 0, 0, 0};
    if ((T0 & (LL - 1)) != 0) pv = *(const u16x8*)(base - 8);

    float4 w = ((const float4*)cw)[i];
    float bs = cb[i];
    float xm3 = bits2f(pv[5]), xm2 = bits2f(pv[6]), xm1 = bits2f(pv[7]);
    u16x8 o0, o1;
    #pragma unroll
    for (int tt = 0; tt < 16; ++tt) {
        float x0 = bits2f(tt < 8 ? m0[tt] : m1[tt - 8]);
        float acc = bs;
        acc = fmaf(xm3, w.x, acc);
        acc = fmaf(xm2, w.y, acc);
        acc = fmaf(xm1, w.z, acc);
        acc = fmaf(x0,  w.w, acc);
        ushort_t ob = f2b_bits(acc / (1.f + __expf(-acc)));
        if (tt < 8) o0[tt] = ob; else o1[tt - 8] = ob;
        xm3 = xm2; xm2 = xm1; xm1 = x0;
    }
    ushort_t* dt = (ushort_t*)xcT + (size_t)i * ROWS + T0;
    *(u16x8*)dt = o0;
    *(u16x8*)(dt + 8) = o1;
    *(u16x8*)&tile[lc * 72 + tg * 16] = o0;
    *(u16x8*)&tile[lc * 72 + tg * 16 + 8] = o1;
    __syncthreads();
    const int lt = threadIdx.x >> 2, cg = threadIdx.x & 3;
    u16x8 q0, q1;
    #pragma unroll
    for (int j = 0; j < 8; ++j) q0[j] = tile[(cg * 16 + j) * 72 + lt];
    #pragma unroll
    for (int j = 8; j < 16; ++j) q1[j - 8] = tile[(cg * 16 + j) * 72 + lt];
    ushort_t* wp = (ushort_t*)xc + (size_t)(T0b + lt) * DI + ch0 + cg * 16;
    *(u16x8*)wp = q0;
    *(u16x8*)(wp + 8) = q1;
}

// ---------------------------------------------------------------------------
// FUSED chunked selective scan. R11 config (measured best: bf16 ssm, __expf,
// 16 ch x 64 chunks) + packed-fp32 (VOP3P) state pairs:
// h2/p2/y2 are float2 -> v_pk_fma_f32 / v_pk_mul_f32 halve those VALU slots.
// exp/clamp stay scalar (no pk forms); a[] stays SGPR (VGPR budget < 64 cap).
// ---------------------------------------------------------------------------
__global__ __launch_bounds__(1024)
void scan_fused(const bf16* __restrict__ xcT, const bf16* __restrict__ dT,
                const bf16* __restrict__ ssm, const bf16* __restrict__ xrbT,
                const float* __restrict__ A_log, const float* __restrict__ Dskip,
                bf16* __restrict__ ybf)
{
    __shared__ uint_t lsum[DS * NC * 16];   // 64 KB

    const int tid = threadIdx.x;
    const int b = blockIdx.x >> 6;
    const int ch0 = (blockIdx.x & 63) << 4;
    const int chl = tid & 15;
    const int c = tid >> 4;                  // chunk 0..63
    const int i = ch0 + chl;
    const size_t tb = (size_t)b * LL + c * CT;

    // A_log -> SGPRs (wave-uniform broadcast)
    float a[DS];
    #pragma unroll
    for (int s = 0; s < DS; ++s) {
        uint_t bits = (uint_t)__builtin_amdgcn_readfirstlane((int)__float_as_uint(A_log[s]));
        a[s] = __uint_as_float(bits);
    }

    const u16x8* dp = (const u16x8*)((const ushort_t*)dT + (size_t)i * ROWS + tb);
    const u16x8* up = (const u16x8*)((const ushort_t*)xcT + (size_t)i * ROWS + tb);
    const u16x8* rp = (const u16x8*)((const ushort_t*)xrbT + (size_t)(1024 + i) * ROWS + tb);

    f32x2 h2[8], p2[8];
    #pragma unroll
    for (int k = 0; k < 8; ++k) {
        h2[k] = (f32x2){0.f, 0.f};
        p2[k] = (f32x2){1.f, 1.f};
    }

    // ---- Pass A: chunk recurrence from h=0
    #pragma unroll
    for (int half = 0; half < 2; ++half) {
        u16x8 dv8 = dp[half];
        u16x8 uv8 = up[half];
        #pragma unroll
        for (int t = 0; t < 8; ++t) {
            float dv = bits2f(dv8[t]);
            float uv = bits2f(uv8[t]);
            float du = dv * uv;
            f32x2 du2 = {du, du};
            const u16x8* sp = (const u16x8*)((const ushort_t*)ssm + (tb + half * 8 + t) * 64);
            u16x8 B0 = sp[0], B1 = sp[1];
            #pragma unroll
            for (int k = 0; k < 8; ++k) {
                float eA = fminf(fmaxf(dv * a[2 * k],     -5.f), 5.f);
                float eB = fminf(fmaxf(dv * a[2 * k + 1], -5.f), 5.f);
                f32x2 dA = {__expf(eA), __expf(eB)};
                f32x2 Bv = {bits2f(k < 4 ? B0[2 * k] : B1[2 * k - 8]),
                            bits2f(k < 4 ? B0[2 * k + 1] : B1[2 * k - 7])};
                h2[k] = dA * h2[k] + du2 * Bv;
                p2[k] = p2[k] * dA;
            }
        }
    }
    #pragma unroll
    for (int k = 0; k < 8; ++k) {
        lsum[(2 * k) * 1024 + tid] =
            (uint_t)f2b_bits(p2[k][0]) | ((uint_t)f2b_bits(h2[k][0]) << 16);
        lsum[(2 * k + 1) * 1024 + tid] =
            (uint_t)f2b_bits(p2[k][1]) | ((uint_t)f2b_bits(h2[k][1]) << 16);
    }
    __syncthreads();

    // ---- Combine (threads 0..255): (chl,s) serial over 64 chunks
    if (tid < 256) {
        int cl = tid & 15, s = tid >> 4;
        float hh = 0.f;
        for (int cc = 0; cc < NC; ++cc) {
            int off = s * 1024 + cc * 16 + cl;
            uint_t wrd = lsum[off];
            float pp = bits2f((ushort_t)(wrd & 0xFFFF));
            float qq = bits2f((ushort_t)(wrd >> 16));
            lsum[off] = (uint_t)f2b_bits(hh);      // h at chunk start
            hh = fmaf(pp, hh, qq);
        }
    }
    __syncthreads();

    #pragma unroll
    for (int k = 0; k < 8; ++k) {
        h2[k][0] = bits2f((ushort_t)lsum[(2 * k) * 1024 + tid]);
        h2[k][1] = bits2f((ushort_t)lsum[(2 * k + 1) * 1024 + tid]);
    }

    const float dsk = Dskip[i];

    // ---- Pass C: rerun from true h_start, emit gated y (row-major)
    #pragma unroll
    for (int half = 0; half < 2; ++half) {
        u16x8 dv8 = dp[half];
        u16x8 uv8 = up[half];
        u16x8 rv8 = rp[half];
        #pragma unroll
        for (int t = 0; t < 8; ++t) {
            float dv = bits2f(dv8[t]);
            float uv = bits2f(uv8[t]);
            float du = dv * uv;
            f32x2 du2 = {du, du};
            const u16x8* sp = (const u16x8*)((const ushort_t*)ssm + (tb + half * 8 + t) * 64);
            u16x8 B0 = sp[0], B1 = sp[1], C0 = sp[2], C1 = sp[3];
            f32x2 y2 = {0.f, 0.f};
            #pragma unroll
            for (int k = 0; k < 8; ++k) {
                float eA = fminf(fmaxf(dv * a[2 * k],     -5.f), 5.f);
                float eB = fminf(fmaxf(dv * a[2 * k + 1], -5.f), 5.f);
                f32x2 dA = {__expf(eA), __expf(eB)};
                f32x2 Bv = {bits2f(k < 4 ? B0[2 * k] : B1[2 * k - 8]),
                            bits2f(k < 4 ? B0[2 * k + 1] : B1[2 * k - 7])};
                f32x2 Cv = {bits2f(k < 4 ? C0[2 * k] : C1[2 * k - 8]),
                            bits2f(k < 4 ? C0[2 * k + 1] : C1[2 * k - 7])};
                h2[k] = dA * h2[k] + du2 * Bv;
                y2 = y2 + h2[k] * Cv;
            }
            float y = y2[0] + y2[1];
            float res = bits2f(rv8[t]);
            float g = res / (1.f + __expf(-res));
            ybf[(tb + half * 8 + t) * DI + i] = __float2bfloat16((y + uv * dsk) * g);
        }
    }
}

// ---------------------------------------------------------------------------
// r = outp(bf16) + clip(x_raw); LayerNorm over 512; dtype detected locally.
// ---------------------------------------------------------------------------
__global__ __launch_bounds__(256)
void ln_kernel(const bf16* __restrict__ outp, const void* __restrict__ xsrc,
               const void* __restrict__ wdt_probe,
               const float* __restrict__ gamma, const float* __restrict__ beta,
               void* __restrict__ out)
{
    const int isbf = detect_local((const ushort_t*)wdt_probe);
    const int row = blockIdx.x;
    const int tid = threadIdx.x;

    float r[2];
    float sum = 0.f, ss = 0.f;
    #pragma unroll
    for (int q = 0; q < 2; ++q) {
        int j = tid + q * 256;
        float xv = load_flag(xsrc, row * DM + j, isbf);
        xv = fminf(fmaxf(xv, -10.f), 10.f);
        float v = b2f(outp[(size_t)row * DM + j]) + xv;
        r[q] = v;
        sum += v;
        ss = fmaf(v, v, ss);
    }
    #pragma unroll
    for (int off = 32; off >= 1; off >>= 1) {
        sum += __shfl_down(sum, off);
        ss  += __shfl_down(ss, off);
    }
    __shared__ float s1[4], s2[4];
    __shared__ float stats[2];
    int wid = tid >> 6, lane = tid & 63;
    if (lane == 0) { s1[wid] = sum; s2[wid] = ss; }
    __syncthreads();
    if (tid == 0) {
        float S = s1[0] + s1[1] + s1[2] + s1[3];
        float Qq = s2[0] + s2[1] + s2[2] + s2[3];
        float mean = S / DM;
        float var = Qq / DM - mean * mean;
        stats[0] = mean;
        stats[1] = rsqrtf(var + 1e-5f);
    }
    __syncthreads();
    float mean = stats[0], rstd = stats[1];
    #pragma unroll
    for (int q = 0; q < 2; ++q) {
        int j = tid + q * 256;
        float v = (r[q] - mean) * rstd * gamma[j] + beta[j];
        size_t o = (size_t)row * DM + j;
        if (isbf) ((bf16*)out)[o] = __float2bfloat16(v);
        else      ((float*)out)[o] = v;
    }
}

// ---------------------------------------------------------------------------
extern "C" void kernel_launch(void* const* d_in, const int* in_sizes, int n_in,
                              void* d_out, int out_size, void* d_ws, size_t ws_size,
                              hipStream_t stream)
{
    float* W = (float*)d_ws;
    float* ccw  = W;                       // 4096
    float* ccb  = ccw  + 4096;             // 1024
    float* cAlg = ccb  + 1024;             // 16
    float* cDsk = cAlg + 16;               // 1024
    float* cgam = cDsk + 1024;             // 512
    float* cbet = cgam + 512;              // 512
    float* bdtx = cbet + 512;              // 1152  (total 8336 floats)
    bf16*  xbf  = (bf16*)(bdtx + 1152);    // 4096x512
    bf16*  xrbT = xbf  + 2097152;          // 2048x4096 (x_and_res transposed)
    bf16*  xcT  = xrbT + 8388608;          // 1024x4096 (xc transposed)
    bf16*  xc   = xcT  + 4194304;          // 4096x1024 (xc row-major)
    bf16*  ybf  = xc   + 4194304;          // 4096x1024
    bf16*  dT   = ybf  + 4194304;          // 1024x4096 (delta transposed)
    bf16*  ssm  = dT   + 4194304;          // 4096x64 bf16 (B|C|pad row-major)
    bf16*  outp = ssm  + 262144;           // 4096x512 bf16
    bf16*  WtIn = outp + 2097152;          // 2048x512
    bf16*  WtDtx= WtIn + 1048576;          // 1152x1024 (W_dt|W_x|0)
    bf16*  WtOut= WtDtx+ 1179648;          // 512x1024

    // 1) all prep (dtype detect per block, pack x, transposes, small params)
    prep_all<<<5057, 256, 0, stream>>>(
        d_in[0], d_in[1], d_in[5], d_in[4], d_in[9], d_in[2], d_in[3],
        d_in[7], d_in[8], d_in[10], d_in[11], d_in[6],
        xbf, WtIn, WtDtx, WtOut, ccw, ccb, cAlg, cDsk, cgam, cbet, bdtx);

    // 2) x_and_res^T = (clip(x) @ W_in)^T    [2048][4096] bf16, 128x128 tile
    gemm_mfma<128, 128, true, true, false><<<dim3(2048 / 128, ROWS / 128), 256, 0, stream>>>(
        xbf, WtIn, nullptr, xrbT, nullptr, ROWS, 2048, 512);

    // 3) depthwise causal conv + SiLU -> xcT + xc (dual layout)
    conv_silu<<<1024, 256, 0, stream>>>(xrbT, ccw, ccb, xcT, xc);

    // 4) fused delta^T | ssm GEMM: n<1024 -> dT[n][m] bf16; [1024,1088) -> ssm bf16
    gemm_mfma<64, 128, true, true, true><<<dim3(NDTX / 128, ROWS / 64), 256, 0, stream>>>(
        xc, WtDtx, bdtx, dT, ssm, ROWS, NDTX, DI);

    // 5) fused chunked selective scan -> gated y row-major (256 blocks)
    scan_fused<<<256, 1024, 0, stream>>>(xcT, dT, ssm, xrbT, cAlg, cDsk, ybf);

    // 6) out_pre = y @ W_out                 [4096][512] bf16
    gemm_mfma<64, 64, true, false, false><<<dim3(DM / 64, ROWS / 64), 256, 0, stream>>>(
        ybf, WtOut, nullptr, outp, nullptr, ROWS, DM, DI);

    // 7) LayerNorm(out_pre + clip(x)) -> out (dtype detected locally)
    ln_kernel<<<ROWS, 256, 0, stream>>>(outp, d_in[0], d_in[5], cgam, cbet, d_out);
}